// Round 1
// baseline (293.068 us; speedup 1.0000x reference)
//
#include <hip/hip_runtime.h>

#define B        4
#define N        16384
#define NPOINT   2048
#define C        64
#define NSAMPLE  32
#define CH       (C + 3)     // 67 output channels
#define RADIUS2  0.01f

// ---------------------------------------------------------------------------
// Kernel 1: transpose features (B,C,N) -> (B,N,C) so per-point channel
// vectors are contiguous (256 B) for the gather.
// grid = (N/64, B), block = 256
// ---------------------------------------------------------------------------
__global__ __launch_bounds__(256) void feat_transpose_kernel(
    const float* __restrict__ f,   // (B,C,N)
    float* __restrict__ ft)        // (B,N,C)
{
    __shared__ float tile[64][65];          // +1 pad: conflict-free both ways
    const int b  = blockIdx.y;
    const int n0 = blockIdx.x * 64;
    const int tx = threadIdx.x & 63;        // 0..63
    const int ty = threadIdx.x >> 6;        // 0..3

    for (int cc = ty; cc < C; cc += 4)      // coalesced read along N
        tile[cc][tx] = f[((size_t)b * C + cc) * N + n0 + tx];
    __syncthreads();
    for (int nn = ty; nn < 64; nn += 4)     // coalesced write along C
        ft[((size_t)b * N + n0 + nn) * C + tx] = tile[tx][nn];
}

// ---------------------------------------------------------------------------
// Kernel 2: one 256-thread block per query point.
//   Phase 1 (wave 0): ordered ball query via ballot + prefix popcount.
//   Phase 2 (all):    gather 67 channels x 32 slots into padded LDS tile,
//                     then coalesced store in (B,ch,npoint,nsample) layout.
// ---------------------------------------------------------------------------
template <bool TRANSPOSED>
__global__ __launch_bounds__(256) void qg_kernel(
    const float* __restrict__ xyz,      // (B,N,3)
    const float* __restrict__ new_xyz,  // (B,NPOINT,3)
    const float* __restrict__ feat,     // TRANSPOSED ? (B,N,C) : (B,C,N)
    float* __restrict__ out_cnt,        // B*NPOINT (cnt as float)
    float* __restrict__ out_feat)       // (B,CH,NPOINT,NSAMPLE)
{
    const int q = blockIdx.x;           // 0 .. B*NPOINT-1
    const int b = q / NPOINT;
    const int j = q % NPOINT;
    const int t = threadIdx.x;

    __shared__ int   s_idx[NSAMPLE];
    __shared__ float s_tile[CH * 33];   // stride 33 -> conflict-free
    __shared__ int   s_cnt;

    const float qx = new_xyz[q * 3 + 0];
    const float qy = new_xyz[q * 3 + 1];
    const float qz = new_xyz[q * 3 + 2];

    // ---- Phase 1: ball query (wave 0 only; t<64 is wave-uniform) ----
    if (t < 64) {
        const float* xb = xyz + (size_t)b * N * 3;
        int cnt = 0;
        for (int base = 0; base < N; base += 64) {   // N % 64 == 0
            const int p = base + t;
            const float dx = xb[p * 3 + 0] - qx;
            const float dy = xb[p * 3 + 1] - qy;
            const float dz = xb[p * 3 + 2] - qz;
            const float d2 = dx * dx + dy * dy + dz * dz;
            const bool in = d2 < RADIUS2;
            const unsigned long long m = __ballot(in);
            if (in) {
                const int slot = cnt + __popcll(m & ((1ull << t) - 1ull));
                if (slot < NSAMPLE) s_idx[slot] = p;
            }
            cnt += __popcll(m);
            if (cnt >= NSAMPLE) break;               // cnt caps at NSAMPLE
        }
        if (t == 0) {
            const int c = cnt < NSAMPLE ? cnt : NSAMPLE;
            s_cnt = c;
            out_cnt[q] = (float)c;                   // int32 cnt stored as f32
        }
    }
    __syncthreads();

    const int cnt = s_cnt;
    // fill unfound slots with first index (0 if none); no race: when cnt>0
    // writers are t>=cnt>=1 and only read slot 0; when cnt==0 nobody reads.
    if (t < NSAMPLE && t >= cnt) {
        s_idx[t] = (cnt > 0) ? s_idx[0] : 0;
    }
    __syncthreads();

    // ---- Phase 2a: gather into LDS tile (ch-major, padded) ----
    {
        const int k = t >> 3;                        // 0..31 slot
        const int s = t & 7;                         // 0..7 channel octet
        const int i = s_idx[k];
        if (TRANSPOSED) {
            const float* fp = feat + ((size_t)b * N + i) * C + s * 8;
            const float4 v0 = *(const float4*)(fp);
            const float4 v1 = *(const float4*)(fp + 4);
            const int ch = 3 + s * 8;
            s_tile[(ch + 0) * 33 + k] = v0.x;
            s_tile[(ch + 1) * 33 + k] = v0.y;
            s_tile[(ch + 2) * 33 + k] = v0.z;
            s_tile[(ch + 3) * 33 + k] = v0.w;
            s_tile[(ch + 4) * 33 + k] = v1.x;
            s_tile[(ch + 5) * 33 + k] = v1.y;
            s_tile[(ch + 6) * 33 + k] = v1.z;
            s_tile[(ch + 7) * 33 + k] = v1.w;
        } else {
            #pragma unroll
            for (int cc = 0; cc < 8; ++cc) {
                const int c = s * 8 + cc;
                s_tile[(3 + c) * 33 + k] = feat[((size_t)b * C + c) * N + i];
            }
        }
    }
    // xyz channels 0..2 (relative coords)
    if (t < NSAMPLE) {
        const int i = s_idx[t];
        const float* xp = xyz + ((size_t)b * N + i) * 3;
        s_tile[0 * 33 + t] = xp[0] - qx;
        s_tile[1 * 33 + t] = xp[1] - qy;
        s_tile[2 * 33 + t] = xp[2] - qz;
    }
    __syncthreads();

    // ---- Phase 2b: coalesced store ----
    for (int e = t; e < CH * NSAMPLE; e += 256) {
        const int ch = e >> 5;
        const int k  = e & 31;
        out_feat[(((size_t)b * CH + ch) * NPOINT + j) * NSAMPLE + k] =
            s_tile[ch * 33 + k];
    }
}

extern "C" void kernel_launch(void* const* d_in, const int* in_sizes, int n_in,
                              void* d_out, int out_size, void* d_ws, size_t ws_size,
                              hipStream_t stream) {
    const float* xyz      = (const float*)d_in[0];   // (B,N,3)
    const float* new_xyz  = (const float*)d_in[1];   // (B,NPOINT,3)
    const float* features = (const float*)d_in[2];   // (B,C,N)

    float* out_cnt  = (float*)d_out;                 // B*NPOINT
    float* out_feat = out_cnt + (size_t)B * NPOINT;  // (B,CH,NPOINT,NSAMPLE)

    const size_t ft_bytes = (size_t)B * N * C * sizeof(float);
    if (ws_size >= ft_bytes) {
        float* ft = (float*)d_ws;
        feat_transpose_kernel<<<dim3(N / 64, B), 256, 0, stream>>>(features, ft);
        qg_kernel<true><<<B * NPOINT, 256, 0, stream>>>(xyz, new_xyz, ft,
                                                        out_cnt, out_feat);
    } else {
        qg_kernel<false><<<B * NPOINT, 256, 0, stream>>>(xyz, new_xyz, features,
                                                         out_cnt, out_feat);
    }
}

// Round 2
// 220.285 us; speedup vs baseline: 1.3304x; 1.3304x over previous
//
#include <hip/hip_runtime.h>

#define B        4
#define N        16384
#define NPOINT   2048
#define C        64
#define NSAMPLE  32
#define CH       (C + 3)     // 67 output channels
#define RADIUS2  0.01f

// ---------------------------------------------------------------------------
// Kernel 1: transpose features (B,C,N) -> (B,N,C) so per-point channel
// vectors are contiguous (256 B) for the gather.
// grid = (N/64, B), block = 256
// ---------------------------------------------------------------------------
__global__ __launch_bounds__(256) void feat_transpose_kernel(
    const float* __restrict__ f,   // (B,C,N)
    float* __restrict__ ft)        // (B,N,C)
{
    __shared__ float tile[64][65];          // +1 pad: conflict-free both ways
    const int b  = blockIdx.y;
    const int n0 = blockIdx.x * 64;
    const int tx = threadIdx.x & 63;        // 0..63
    const int ty = threadIdx.x >> 6;        // 0..3

    for (int cc = ty; cc < C; cc += 4)      // coalesced read along N
        tile[cc][tx] = f[((size_t)b * C + cc) * N + n0 + tx];
    __syncthreads();
    for (int nn = ty; nn < 64; nn += 4)     // coalesced write along C
        ft[((size_t)b * N + n0 + nn) * C + tx] = tile[tx][nn];
}

// ---------------------------------------------------------------------------
// Kernel 2: ONE WAVE (64 threads) per query point. All resident waves scan
// (no idle waves at barriers; 16 blocks/CU = 16 scan-waves/CU).
//   Phase 1: ordered ball query, 128 pts/iter, software-pipelined prefetch
//            of the next 128 pts issued BEFORE the early-exit check.
//   Phase 2: gather 67 channels x 32 slots into padded LDS tile (stride 33),
//            then coalesced store in (B,ch,npoint,nsample) layout.
// cnt is wave-uniform (ballot/popcount) -> lives in registers, no LDS flag.
// ---------------------------------------------------------------------------
template <bool TRANSPOSED>
__global__ __launch_bounds__(64) void qg_wave_kernel(
    const float* __restrict__ xyz,      // (B,N,3)
    const float* __restrict__ new_xyz,  // (B,NPOINT,3)
    const float* __restrict__ feat,     // TRANSPOSED ? (B,N,C) : (B,C,N)
    float* __restrict__ out_cnt,        // B*NPOINT (cnt as float)
    float* __restrict__ out_feat)       // (B,CH,NPOINT,NSAMPLE)
{
    const int q = blockIdx.x;           // 0 .. B*NPOINT-1
    const int b = q >> 11;              // q / NPOINT
    const int j = q & (NPOINT - 1);     // q % NPOINT
    const int l = threadIdx.x;          // 0..63

    __shared__ int   s_idx[NSAMPLE];
    __shared__ float s_tile[CH * 33];   // stride 33 -> conflict-free

    const float qx = new_xyz[q * 3 + 0];
    const float qy = new_xyz[q * 3 + 1];
    const float qz = new_xyz[q * 3 + 2];

    const float* xb = xyz + (size_t)b * N * 3;

    // ---- Phase 1: pipelined ordered ball query ----
    int cnt = 0;
    {
        // preload first 128 points (two 64-pt groups per lane)
        float x0 = xb[l * 3 + 0], y0 = xb[l * 3 + 1], z0 = xb[l * 3 + 2];
        float x1 = xb[(64 + l) * 3 + 0], y1 = xb[(64 + l) * 3 + 1],
              z1 = xb[(64 + l) * 3 + 2];

        for (int base = 0; base < N; base += 128) {   // N % 128 == 0
            // prefetch next 128 before any dependent work / break
            float nx0 = 0.f, ny0 = 0.f, nz0 = 0.f;
            float nx1 = 0.f, ny1 = 0.f, nz1 = 0.f;
            const int nb = base + 128;
            if (nb < N) {
                nx0 = xb[(nb + l) * 3 + 0];
                ny0 = xb[(nb + l) * 3 + 1];
                nz0 = xb[(nb + l) * 3 + 2];
                nx1 = xb[(nb + 64 + l) * 3 + 0];
                ny1 = xb[(nb + 64 + l) * 3 + 1];
                nz1 = xb[(nb + 64 + l) * 3 + 2];
            }

            // group 0
            {
                const float dx = x0 - qx, dy = y0 - qy, dz = z0 - qz;
                const float d2 = dx * dx + dy * dy + dz * dz;
                const bool in = d2 < RADIUS2;
                const unsigned long long m = __ballot(in);
                if (in) {
                    const int slot = cnt + __popcll(m & ((1ull << l) - 1ull));
                    if (slot < NSAMPLE) s_idx[slot] = base + l;
                }
                cnt += __popcll(m);
            }
            // group 1
            {
                const float dx = x1 - qx, dy = y1 - qy, dz = z1 - qz;
                const float d2 = dx * dx + dy * dy + dz * dz;
                const bool in = d2 < RADIUS2;
                const unsigned long long m = __ballot(in);
                if (in) {
                    const int slot = cnt + __popcll(m & ((1ull << l) - 1ull));
                    if (slot < NSAMPLE) s_idx[slot] = base + 64 + l;
                }
                cnt += __popcll(m);
            }
            if (cnt >= NSAMPLE) break;
            x0 = nx0; y0 = ny0; z0 = nz0;
            x1 = nx1; y1 = ny1; z1 = nz1;
        }
        if (cnt > NSAMPLE) cnt = NSAMPLE;   // wave-uniform
    }

    if (l == 0) out_cnt[q] = (float)cnt;    // int32 cnt stored as f32 bits? no: value
    __syncthreads();                        // s_idx appends visible

    // fill unfound slots with first index (0 if none); writers are l>=cnt>=1
    // and read only slot 0, which nobody writes.
    if (l < NSAMPLE && l >= cnt) {
        s_idx[l] = (cnt > 0) ? s_idx[0] : 0;
    }
    __syncthreads();

    // ---- Phase 2a: gather into LDS tile (ch-major, stride 33) ----
    if (TRANSPOSED) {
        #pragma unroll
        for (int p = 0; p < 8; ++p) {
            const int k  = p * 4 + (l >> 4);     // slot 0..31
            const int c4 = l & 15;               // float4 index within 64 ch
            const int i  = s_idx[k];
            const float4 v =
                ((const float4*)(feat + ((size_t)b * N + i) * C))[c4];
            const int ch = 3 + c4 * 4;
            s_tile[(ch + 0) * 33 + k] = v.x;
            s_tile[(ch + 1) * 33 + k] = v.y;
            s_tile[(ch + 2) * 33 + k] = v.z;
            s_tile[(ch + 3) * 33 + k] = v.w;
        }
    } else {
        #pragma unroll
        for (int p = 0; p < 8; ++p) {
            const int k  = p * 4 + (l >> 4);
            const int c4 = l & 15;
            const int i  = s_idx[k];
            #pragma unroll
            for (int cc = 0; cc < 4; ++cc) {
                const int c = c4 * 4 + cc;
                s_tile[(3 + c) * 33 + k] =
                    feat[((size_t)b * C + c) * N + i];
            }
        }
    }
    // xyz channels 0..2 (relative coords)
    if (l < NSAMPLE) {
        const int i = s_idx[l];
        const float* xp = xyz + ((size_t)b * N + i) * 3;
        s_tile[0 * 33 + l] = xp[0] - qx;
        s_tile[1 * 33 + l] = xp[1] - qy;
        s_tile[2 * 33 + l] = xp[2] - qz;
    }
    __syncthreads();

    // ---- Phase 2b: coalesced store (k-contiguous 128B segments) ----
    for (int e = l; e < CH * NSAMPLE; e += 64) {
        const int ch = e >> 5;
        const int k  = e & 31;
        out_feat[(((size_t)b * CH + ch) * NPOINT + j) * NSAMPLE + k] =
            s_tile[ch * 33 + k];
    }
}

extern "C" void kernel_launch(void* const* d_in, const int* in_sizes, int n_in,
                              void* d_out, int out_size, void* d_ws, size_t ws_size,
                              hipStream_t stream) {
    const float* xyz      = (const float*)d_in[0];   // (B,N,3)
    const float* new_xyz  = (const float*)d_in[1];   // (B,NPOINT,3)
    const float* features = (const float*)d_in[2];   // (B,C,N)

    float* out_cnt  = (float*)d_out;                 // B*NPOINT
    float* out_feat = out_cnt + (size_t)B * NPOINT;  // (B,CH,NPOINT,NSAMPLE)

    const size_t ft_bytes = (size_t)B * N * C * sizeof(float);
    if (ws_size >= ft_bytes) {
        float* ft = (float*)d_ws;
        feat_transpose_kernel<<<dim3(N / 64, B), 256, 0, stream>>>(features, ft);
        qg_wave_kernel<true><<<B * NPOINT, 64, 0, stream>>>(xyz, new_xyz, ft,
                                                            out_cnt, out_feat);
    } else {
        qg_wave_kernel<false><<<B * NPOINT, 64, 0, stream>>>(xyz, new_xyz, features,
                                                             out_cnt, out_feat);
    }
}

// Round 3
// 126.304 us; speedup vs baseline: 2.3203x; 1.7441x over previous
//
#include <hip/hip_runtime.h>

#define B        4
#define N        16384       // 2^14
#define NPOINT   2048        // 2^11
#define C        64
#define NSAMPLE  32
#define CH       (C + 3)     // 67 output channels
#define RADIUS2  0.01f
#define NCELL    1000        // 10^3 cells per batch (cell size = radius)
#define CSTRIDE  1032        // cell_start row stride (ints) >= NCELL+1
#define CCSTRIDE 1024        // counter row stride (ints)
#define CAP      256         // per-query candidate cap (mean ~68, 22 sigma)

__device__ __forceinline__ int clamp10(int v) {
    return v < 0 ? 0 : (v > 9 ? 9 : v);
}

// ---------------------------------------------------------------------------
// Grid build kernel 0: zero the per-cell counters (ws is poisoned each call).
// ---------------------------------------------------------------------------
__global__ __launch_bounds__(256) void zero_kernel(int* __restrict__ p, int n) {
    const int i = blockIdx.x * 256 + threadIdx.x;
    if (i < n) p[i] = 0;
}

// ---------------------------------------------------------------------------
// Grid build kernel 1: count points per cell.
// ---------------------------------------------------------------------------
__global__ __launch_bounds__(256) void count_kernel(const float* __restrict__ xyz,
                                                    int* __restrict__ cnt) {
    const int g = blockIdx.x * 256 + threadIdx.x;   // < B*N
    const int b = g >> 14;
    const float x = xyz[g * 3 + 0], y = xyz[g * 3 + 1], z = xyz[g * 3 + 2];
    const int cx = clamp10((int)(x * 10.f));
    const int cy = clamp10((int)(y * 10.f));
    const int cz = clamp10((int)(z * 10.f));
    atomicAdd(&cnt[(b << 10) + (cx * 10 + cy) * 10 + cz], 1);
}

// ---------------------------------------------------------------------------
// Grid build kernel 2: exclusive scan (1000 cells/batch, Hillis-Steele).
// Writes cell_start[0..1000] and re-inits cnt[] as the scatter cursor.
// grid = B, block = 1024
// ---------------------------------------------------------------------------
__global__ __launch_bounds__(1024) void prefix_kernel(int* __restrict__ cnt,
                                                      int* __restrict__ cs) {
    __shared__ int s[1024];
    const int t = threadIdx.x, b = blockIdx.x;
    const int v = (t < NCELL) ? cnt[(b << 10) + t] : 0;
    s[t] = v;
    __syncthreads();
    for (int off = 1; off < 1024; off <<= 1) {
        const int u = (t >= off) ? s[t - off] : 0;
        __syncthreads();
        s[t] += u;
        __syncthreads();
    }
    const int excl = (t == 0) ? 0 : s[t - 1];       // exclusive prefix
    if (t <= NCELL) cs[b * CSTRIDE + t] = excl;     // t==1000 -> total
    if (t < NCELL)  cnt[(b << 10) + t] = excl;      // cursor init
}

// ---------------------------------------------------------------------------
// Grid build kernel 3: scatter points into cell-sorted array as
// float4(x,y,z, bitcast(orig_index)).
// ---------------------------------------------------------------------------
__global__ __launch_bounds__(256) void scatter_kernel(const float* __restrict__ xyz,
                                                      int* __restrict__ cursor,
                                                      float4* __restrict__ sp) {
    const int g = blockIdx.x * 256 + threadIdx.x;
    const int b = g >> 14;
    const int n = g & (N - 1);
    const float x = xyz[g * 3 + 0], y = xyz[g * 3 + 1], z = xyz[g * 3 + 2];
    const int cx = clamp10((int)(x * 10.f));
    const int cy = clamp10((int)(y * 10.f));
    const int cz = clamp10((int)(z * 10.f));
    const int cell = (cx * 10 + cy) * 10 + cz;
    const int pos = atomicAdd(&cursor[(b << 10) + cell], 1);
    sp[(b << 14) + pos] = make_float4(x, y, z, __int_as_float(n));
}

// ---------------------------------------------------------------------------
// Transpose features (B,C,N) -> (B,N,C), float4-vectorized both directions.
// grid = (N/64, B), block = 256
// ---------------------------------------------------------------------------
__global__ __launch_bounds__(256) void feat_transpose_kernel(
    const float* __restrict__ f,   // (B,C,N)
    float* __restrict__ ft)        // (B,N,C)
{
    __shared__ float tile[64][65];
    const int b  = blockIdx.y;
    const int n0 = blockIdx.x * 64;
    const int t  = threadIdx.x;
    const int r16 = t >> 4;                  // 0..15
    const int x4  = t & 15;                  // 0..15
    #pragma unroll
    for (int it = 0; it < 4; ++it) {
        const int cc = it * 16 + r16;
        const float4 v = *(const float4*)(f + ((size_t)b * C + cc) * N + n0 + x4 * 4);
        tile[cc][x4 * 4 + 0] = v.x;
        tile[cc][x4 * 4 + 1] = v.y;
        tile[cc][x4 * 4 + 2] = v.z;
        tile[cc][x4 * 4 + 3] = v.w;
    }
    __syncthreads();
    #pragma unroll
    for (int it = 0; it < 4; ++it) {
        const int nn = it * 16 + r16;
        float4 v;
        v.x = tile[x4 * 4 + 0][nn];
        v.y = tile[x4 * 4 + 1][nn];
        v.z = tile[x4 * 4 + 2][nn];
        v.w = tile[x4 * 4 + 3][nn];
        *(float4*)(ft + ((size_t)b * N + n0 + nn) * C + x4 * 4) = v;
    }
}

// ---------------------------------------------------------------------------
// Query + group with grid acceleration. One wave (64 thr) per query.
//   Scan: 9 contiguous runs (3x3 xy-cells, z-run contiguous) of the sorted
//         point array; candidates (orig indices) appended to LDS via
//         ballot/prefix-popcount. Full 27-cell count -> exact cnt.
//   Select: rank = #(smaller candidate indices) -> first NSAMPLE in index
//         order, O(K^2/64) with broadcast LDS reads (K ~ 68).
//   Gather: 67 ch x 32 slots via padded LDS tile, float4 in and out.
// ---------------------------------------------------------------------------
__global__ __launch_bounds__(64) void qg_grid_kernel(
    const float*  __restrict__ xyz,      // (B,N,3)
    const float*  __restrict__ new_xyz,  // (B,NPOINT,3)
    const float*  __restrict__ ft,       // (B,N,C)
    const int*    __restrict__ cs,       // cell_start, CSTRIDE per batch
    const float4* __restrict__ sp,       // cell-sorted points
    float* __restrict__ out_cnt,         // B*NPOINT (cnt as float)
    float* __restrict__ out_feat)        // (B,CH,NPOINT,NSAMPLE)
{
    const int q = blockIdx.x;
    const int b = q >> 11;
    const int j = q & (NPOINT - 1);
    const int l = threadIdx.x;

    __shared__ int   cand[CAP];
    __shared__ int   s_idx[NSAMPLE];
    __shared__ float s_tile[CH * 33];    // stride 33 -> conflict-free

    const float qx = new_xyz[q * 3 + 0];
    const float qy = new_xyz[q * 3 + 1];
    const float qz = new_xyz[q * 3 + 2];

    const int cx = clamp10((int)(qx * 10.f));
    const int cy = clamp10((int)(qy * 10.f));
    const int cz = clamp10((int)(qz * 10.f));
    const int z0 = cz > 0 ? cz - 1 : 0;
    const int z1 = cz < 9 ? cz + 1 : 9;

    // prefetch all 9 run bounds in parallel (lanes 0..8), broadcast via shfl
    int sv = 0, ev = 0;
    if (l < 9) {
        const int xx = cx - 1 + l / 3;
        const int yy = cy - 1 + l % 3;
        if (xx >= 0 && xx <= 9 && yy >= 0 && yy <= 9) {
            const int cb = (xx * 10 + yy) * 10;
            sv = cs[b * CSTRIDE + cb + z0];
            ev = cs[b * CSTRIDE + cb + z1 + 1];
        }
    }

    const unsigned long long ltmask = (1ull << l) - 1ull;
    int total = 0, ncand = 0;
    for (int r = 0; r < 9; ++r) {
        const int rs = __shfl(sv, r);
        const int re = __shfl(ev, r);
        for (int p0 = rs; p0 < re; p0 += 64) {
            const int p = p0 + l;
            const bool act = p < re;
            float4 pt = make_float4(1e9f, 1e9f, 1e9f, 0.f);
            if (act) pt = sp[(b << 14) + p];
            const float dx = pt.x - qx, dy = pt.y - qy, dz = pt.z - qz;
            const float d2 = dx * dx + dy * dy + dz * dz;
            const bool in = act && (d2 < RADIUS2);
            const unsigned long long m = __ballot(in);
            if (in) {
                const int slot = ncand + __popcll(m & ltmask);
                if (slot < CAP) cand[slot] = __float_as_int(pt.w);
            }
            const int c = __popcll(m);
            total += c;
            ncand = ncand + c > CAP ? CAP : ncand + c;
        }
    }

    int cntv;
    if (total > CAP) {
        // overflow (astronomically unlikely, uniform data): ordered rescan
        const float* xb = xyz + (size_t)b * N * 3;
        int cnt2 = 0;
        for (int base = 0; base < N; base += 64) {
            const int p = base + l;
            const float dx = xb[p * 3 + 0] - qx;
            const float dy = xb[p * 3 + 1] - qy;
            const float dz = xb[p * 3 + 2] - qz;
            const float d2 = dx * dx + dy * dy + dz * dz;
            const bool in = d2 < RADIUS2;
            const unsigned long long m = __ballot(in);
            if (in) {
                const int slot = cnt2 + __popcll(m & ltmask);
                if (slot < NSAMPLE) s_idx[slot] = p;
            }
            cnt2 += __popcll(m);
            if (cnt2 >= NSAMPLE) break;
        }
        cntv = cnt2 < NSAMPLE ? cnt2 : NSAMPLE;
        __syncthreads();
    } else {
        __syncthreads();                 // cand[] appends visible wave-wide
        const int K = ncand;             // == total
        for (int c = l; c < K; c += 64) {
            const int v = cand[c];
            int rnk = 0;
            for (int i = 0; i < K; ++i) rnk += (cand[i] < v) ? 1 : 0;
            if (rnk < NSAMPLE) s_idx[rnk] = v;   // sorted first-32 by index
        }
        cntv = total < NSAMPLE ? total : NSAMPLE;
        __syncthreads();                 // s_idx writes visible
    }

    if (l == 0) out_cnt[q] = (float)cntv;
    // fill unfound slots with first index (0 if none)
    if (l < NSAMPLE && l >= cntv) s_idx[l] = (cntv > 0) ? s_idx[0] : 0;
    __syncthreads();

    // ---- gather into LDS tile (ch-major, stride 33) ----
    #pragma unroll
    for (int p = 0; p < 8; ++p) {
        const int k  = p * 4 + (l >> 4);         // slot 0..31
        const int c4 = l & 15;                   // float4 within 64 ch
        const int i  = s_idx[k];
        const float4 v = ((const float4*)(ft + ((size_t)b * N + i) * C))[c4];
        const int ch = 3 + c4 * 4;
        s_tile[(ch + 0) * 33 + k] = v.x;
        s_tile[(ch + 1) * 33 + k] = v.y;
        s_tile[(ch + 2) * 33 + k] = v.z;
        s_tile[(ch + 3) * 33 + k] = v.w;
    }
    if (l < NSAMPLE) {
        const int i = s_idx[l];
        const float* xp = xyz + ((size_t)b * N + i) * 3;
        s_tile[0 * 33 + l] = xp[0] - qx;
        s_tile[1 * 33 + l] = xp[1] - qy;
        s_tile[2 * 33 + l] = xp[2] - qz;
    }
    __syncthreads();

    // ---- coalesced float4 stores: 8 lanes cover one 128B (ch,j) line ----
    float4* of4 = (float4*)out_feat;
    for (int e4 = l; e4 < CH * 8; e4 += 64) {
        const int ch = e4 >> 3;
        const int k4 = e4 & 7;
        float4 v;
        v.x = s_tile[ch * 33 + k4 * 4 + 0];
        v.y = s_tile[ch * 33 + k4 * 4 + 1];
        v.z = s_tile[ch * 33 + k4 * 4 + 2];
        v.w = s_tile[ch * 33 + k4 * 4 + 3];
        of4[((size_t)(b * CH + ch) * NPOINT + j) * 8 + k4] = v;
    }
}

// ---------------------------------------------------------------------------
// Fallback (small workspace): round-2 linear-scan kernel.
// ---------------------------------------------------------------------------
template <bool TRANSPOSED>
__global__ __launch_bounds__(64) void qg_wave_kernel(
    const float* __restrict__ xyz,
    const float* __restrict__ new_xyz,
    const float* __restrict__ feat,
    float* __restrict__ out_cnt,
    float* __restrict__ out_feat)
{
    const int q = blockIdx.x;
    const int b = q >> 11;
    const int j = q & (NPOINT - 1);
    const int l = threadIdx.x;

    __shared__ int   s_idx[NSAMPLE];
    __shared__ float s_tile[CH * 33];

    const float qx = new_xyz[q * 3 + 0];
    const float qy = new_xyz[q * 3 + 1];
    const float qz = new_xyz[q * 3 + 2];
    const float* xb = xyz + (size_t)b * N * 3;

    int cnt = 0;
    for (int base = 0; base < N; base += 64) {
        const int p = base + l;
        const float dx = xb[p * 3 + 0] - qx;
        const float dy = xb[p * 3 + 1] - qy;
        const float dz = xb[p * 3 + 2] - qz;
        const float d2 = dx * dx + dy * dy + dz * dz;
        const bool in = d2 < RADIUS2;
        const unsigned long long m = __ballot(in);
        if (in) {
            const int slot = cnt + __popcll(m & ((1ull << l) - 1ull));
            if (slot < NSAMPLE) s_idx[slot] = p;
        }
        cnt += __popcll(m);
        if (cnt >= NSAMPLE) break;
    }
    if (cnt > NSAMPLE) cnt = NSAMPLE;

    if (l == 0) out_cnt[q] = (float)cnt;
    __syncthreads();
    if (l < NSAMPLE && l >= cnt) s_idx[l] = (cnt > 0) ? s_idx[0] : 0;
    __syncthreads();

    #pragma unroll
    for (int p = 0; p < 8; ++p) {
        const int k  = p * 4 + (l >> 4);
        const int c4 = l & 15;
        const int i  = s_idx[k];
        if (TRANSPOSED) {
            const float4 v = ((const float4*)(feat + ((size_t)b * N + i) * C))[c4];
            const int ch = 3 + c4 * 4;
            s_tile[(ch + 0) * 33 + k] = v.x;
            s_tile[(ch + 1) * 33 + k] = v.y;
            s_tile[(ch + 2) * 33 + k] = v.z;
            s_tile[(ch + 3) * 33 + k] = v.w;
        } else {
            #pragma unroll
            for (int cc = 0; cc < 4; ++cc) {
                const int c = c4 * 4 + cc;
                s_tile[(3 + c) * 33 + k] = feat[((size_t)b * C + c) * N + i];
            }
        }
    }
    if (l < NSAMPLE) {
        const int i = s_idx[l];
        const float* xp = xyz + ((size_t)b * N + i) * 3;
        s_tile[0 * 33 + l] = xp[0] - qx;
        s_tile[1 * 33 + l] = xp[1] - qy;
        s_tile[2 * 33 + l] = xp[2] - qz;
    }
    __syncthreads();

    float4* of4 = (float4*)out_feat;
    for (int e4 = l; e4 < CH * 8; e4 += 64) {
        const int ch = e4 >> 3;
        const int k4 = e4 & 7;
        float4 v;
        v.x = s_tile[ch * 33 + k4 * 4 + 0];
        v.y = s_tile[ch * 33 + k4 * 4 + 1];
        v.z = s_tile[ch * 33 + k4 * 4 + 2];
        v.w = s_tile[ch * 33 + k4 * 4 + 3];
        of4[((size_t)(b * CH + ch) * NPOINT + j) * 8 + k4] = v;
    }
}

extern "C" void kernel_launch(void* const* d_in, const int* in_sizes, int n_in,
                              void* d_out, int out_size, void* d_ws, size_t ws_size,
                              hipStream_t stream) {
    const float* xyz      = (const float*)d_in[0];   // (B,N,3)
    const float* new_xyz  = (const float*)d_in[1];   // (B,NPOINT,3)
    const float* features = (const float*)d_in[2];   // (B,C,N)

    float* out_cnt  = (float*)d_out;                 // B*NPOINT
    float* out_feat = out_cnt + (size_t)B * NPOINT;  // (B,CH,NPOINT,NSAMPLE)

    char* ws = (char*)d_ws;
    const size_t ftB = (size_t)B * N * C * sizeof(float);     // 16 MB
    const size_t spB = (size_t)B * N * sizeof(float4);        // 4 MB
    const size_t csB = (size_t)B * CSTRIDE * sizeof(int);
    const size_t ccB = (size_t)B * CCSTRIDE * sizeof(int);
    const size_t need = ftB + spB + csB + ccB;

    if (ws_size >= need) {
        float*  ft = (float*)ws;
        float4* sp = (float4*)(ws + ftB);
        int*    cs = (int*)(ws + ftB + spB);
        int*    cc = (int*)(ws + ftB + spB + csB);
        zero_kernel<<<(B * CCSTRIDE + 255) / 256, 256, 0, stream>>>(cc, B * CCSTRIDE);
        count_kernel<<<B * N / 256, 256, 0, stream>>>(xyz, cc);
        prefix_kernel<<<B, 1024, 0, stream>>>(cc, cs);
        scatter_kernel<<<B * N / 256, 256, 0, stream>>>(xyz, cc, sp);
        feat_transpose_kernel<<<dim3(N / 64, B), 256, 0, stream>>>(features, ft);
        qg_grid_kernel<<<B * NPOINT, 64, 0, stream>>>(xyz, new_xyz, ft, cs, sp,
                                                      out_cnt, out_feat);
    } else if (ws_size >= ftB) {
        float* ft = (float*)ws;
        feat_transpose_kernel<<<dim3(N / 64, B), 256, 0, stream>>>(features, ft);
        qg_wave_kernel<true><<<B * NPOINT, 64, 0, stream>>>(xyz, new_xyz, ft,
                                                            out_cnt, out_feat);
    } else {
        qg_wave_kernel<false><<<B * NPOINT, 64, 0, stream>>>(xyz, new_xyz, features,
                                                             out_cnt, out_feat);
    }
}